// Round 3
// baseline (751.699 us; speedup 1.0000x reference)
//
#include <hip/hip_runtime.h>

// Grid constants (match the JAX reference)
#define NX   480
#define NXC  960
#define NS   (480*480)     // 230400 spatial cells (direct / pooled grids)
#define NSC  (960*960)     // 921600 spatial cells ('cen' grids)
#define CC   64            // channels per source
#define BB   2             // batch

typedef float f4v __attribute__((ext_vector_type(4)));

// R3 probe: PLAIN stores (let L2 write-combine the stream) instead of
// non-temporal. Everything else identical to R2.
__device__ __forceinline__ void st4(float* p, float a, float b, float c, float d) {
    f4v v = {a, b, c, d};
    *(f4v*)p = v;
}

// Gather 4 consecutive channels of winner w's feature row (0-vector if empty).
__device__ __forceinline__ f4v ld4(int w, const float* __restrict__ f, int c) {
    f4v z = {0.0f, 0.0f, 0.0f, 0.0f};
    if (w < 0) return z;                       // exec-mask predicated
    return *(const f4v*)(f + (size_t)w * CC + c);
}

__device__ __forceinline__ f4v max4(f4v a, f4v b) {
    f4v r;
    r.x = fmaxf(a.x, b.x); r.y = fmaxf(a.y, b.y);
    r.z = fmaxf(a.z, b.z); r.w = fmaxf(a.w, b.w);
    return r;
}

// ---------------------------------------------------------------------------
// Pass 1: winner resolution — last point index wins (atomicMax on p).
// All four sources in one dispatch (blockIdx.y selects the source).
// ---------------------------------------------------------------------------
struct SrcDesc { const int* coords; int* winner; int P; int nx; int ns; };

__global__ void __launch_bounds__(256)
scatter_winner4(SrcDesc s0, SrcDesc s1, SrcDesc s2, SrcDesc s3) {
    SrcDesc d = (blockIdx.y == 0) ? s0 : (blockIdx.y == 1) ? s1
              : (blockIdx.y == 2) ? s2 : s3;
    int p = blockIdx.x * 256 + threadIdx.x;
    if (p >= d.P) return;
    int b = d.coords[4*p + 0];
    int y = d.coords[4*p + 2];
    int x = d.coords[4*p + 3];
    atomicMax(&d.winner[b*d.ns + y*d.nx + x], p);
}

// ---------------------------------------------------------------------------
// Pass 2a: direct grids (lidar, radar). Thread owns 4 consecutive cells x all
// 64 channels of ONE source (blockIdx.z). Stores are coalesced 16B plain
// (wave covers 1KB contiguous per store inst; full-line coverage so no
// write-allocate RMW expected). Writes out_{l,r} AND the matching cat
// section, so every output byte is written exactly once, no memset.
// ---------------------------------------------------------------------------
__global__ void __launch_bounds__(256)
dense_direct(const float* __restrict__ lf, const float* __restrict__ rf,
             const int* __restrict__ wl, const int* __restrict__ wr,
             float* __restrict__ out_l, float* __restrict__ out_r,
             float* __restrict__ out_cat)
{
    int s = (blockIdx.x * 256 + threadIdx.x) * 4;   // first of 4 cells
    int b = blockIdx.y;
    int z = blockIdx.z;                              // 0=lidar, 1=radar

    const float* f = z ? rf : lf;
    const int*   w = z ? wr : wl;

    int4 v = *(const int4*)(w + (size_t)b*NS + s);
    int wa[4] = {v.x, v.y, v.z, v.w};

    float* o1 = (z ? out_r : out_l) + (size_t)b*CC*NS + s;
    float* o2 = out_cat + (size_t)b*256*NS + (size_t)(z ? 128 : 0)*NS + s;

    #pragma unroll 2
    for (int g = 0; g < 16; ++g) {
        int c = g * 4;
        f4v x0 = ld4(wa[0], f, c);
        f4v x1 = ld4(wa[1], f, c);
        f4v x2 = ld4(wa[2], f, c);
        f4v x3 = ld4(wa[3], f, c);
        #pragma unroll
        for (int k = 0; k < 4; ++k) {
            size_t cs = (size_t)(c + k) * NS;
            st4(o1 + cs, x0[k], x1[k], x2[k], x3[k]);
            st4(o2 + cs, x0[k], x1[k], x2[k], x3[k]);
        }
    }
}

// ---------------------------------------------------------------------------
// Pass 2b: cen grids (lidar_cen, radar_cen). Thread owns 4 consecutive output
// cells x all 64 channels of ONE source; 2x2 max-pool of sub-cell winner rows
// (max with 0 == reference's pool over the zero-init grid). Writes the cat
// section only.
// ---------------------------------------------------------------------------
__global__ void __launch_bounds__(256)
dense_cen(const float* __restrict__ lcf, const float* __restrict__ rcf,
          const int* __restrict__ wlc, const int* __restrict__ wrc,
          float* __restrict__ out_cat)
{
    int s = (blockIdx.x * 256 + threadIdx.x) * 4;   // first of 4 output cells
    int b = blockIdx.y;
    int z = blockIdx.z;                              // 0=lidar_cen, 1=radar_cen

    const float* f = z ? rcf : lcf;
    const int*   w = z ? wrc : wlc;

    // cen sub-cell winners: rows 2*py, 2*py+1, cols 2*px .. 2*px+7
    int py = s / NX, px = s - py * NX;
    int y0 = py * 2, x0 = px * 2;                    // x0 is 8-aligned
    const int* wb = w + (size_t)b * NSC;
    int4 t0 = *(const int4*)(wb + (size_t)y0*NXC + x0);
    int4 t1 = *(const int4*)(wb + (size_t)y0*NXC + x0 + 4);
    int4 b0 = *(const int4*)(wb + (size_t)(y0+1)*NXC + x0);
    int4 b1 = *(const int4*)(wb + (size_t)(y0+1)*NXC + x0 + 4);
    int wt[8] = {t0.x, t0.y, t0.z, t0.w, t1.x, t1.y, t1.z, t1.w};
    int wbm[8] = {b0.x, b0.y, b0.z, b0.w, b1.x, b1.y, b1.z, b1.w};

    float* o2 = out_cat + (size_t)b*256*NS + (size_t)(z ? 192 : 64)*NS + s;

    #pragma unroll 1
    for (int g = 0; g < 16; ++g) {
        int c = g * 4;
        f4v a[4];
        #pragma unroll
        for (int j = 0; j < 4; ++j) {
            f4v m = ld4(wt[2*j], f, c);
            m = max4(m, ld4(wt[2*j+1],  f, c));
            m = max4(m, ld4(wbm[2*j],   f, c));
            m = max4(m, ld4(wbm[2*j+1], f, c));
            a[j] = m;
        }
        #pragma unroll
        for (int k = 0; k < 4; ++k) {
            size_t cs = (size_t)(c + k) * NS;
            st4(o2 + cs, a[0][k], a[1][k], a[2][k], a[3][k]);
        }
    }
}

extern "C" void kernel_launch(void* const* d_in, const int* in_sizes, int n_in,
                              void* d_out, int out_size, void* d_ws, size_t ws_size,
                              hipStream_t stream) {
    // Inputs per setup_inputs() order
    const float* rc_feat   = (const float*)d_in[0];  // radar_cen
    const int*   rc_coords = (const int*)  d_in[1];
    const float* lc_feat   = (const float*)d_in[2];  // lidar_cen
    const int*   lc_coords = (const int*)  d_in[3];
    const float* l_feat    = (const float*)d_in[4];  // lidar
    const int*   l_coords  = (const int*)  d_in[5];
    const float* r_feat    = (const float*)d_in[6];  // radar
    const int*   r_coords  = (const int*)  d_in[7];

    int P_rc = in_sizes[0] / CC;
    int P_lc = in_sizes[2] / CC;
    int P_l  = in_sizes[4] / CC;
    int P_r  = in_sizes[6] / CC;

    // Output layout (flat, in return order): lidar, radar, cat
    float* out_lidar = (float*)d_out;                 // [2,64,480,480]
    float* out_radar = out_lidar + (size_t)BB*CC*NS;  // [2,64,480,480]
    float* out_cat   = out_radar + (size_t)BB*CC*NS;  // [2,256,480,480]

    // Workspace: winner grids only, init -1 (memset 0xFF)
    int* w_l  = (int*)d_ws;          // [B*NS]
    int* w_r  = w_l  + BB*NS;        // [B*NS]
    int* w_lc = w_r  + BB*NS;        // [B*NSC]
    int* w_rc = w_lc + BB*NSC;       // [B*NSC]
    size_t ws_bytes = (size_t)(2*BB*NS + 2*BB*NSC) * sizeof(int);  // ~18.4 MB

    hipMemsetAsync(d_ws, 0xFF, ws_bytes, stream);

    // Pass 1: winner resolution, one dispatch for all four sources
    SrcDesc s_l  = { l_coords,  w_l,  P_l,  NX,  NS  };
    SrcDesc s_r  = { r_coords,  w_r,  P_r,  NX,  NS  };
    SrcDesc s_lc = { lc_coords, w_lc, P_lc, NXC, NSC };
    SrcDesc s_rc = { rc_coords, w_rc, P_rc, NXC, NSC };
    int maxP = max(max(P_l, P_r), max(P_lc, P_rc));
    dim3 wgrid((maxP + 255) / 256, 4);
    scatter_winner4<<<wgrid, 256, 0, stream>>>(s_l, s_r, s_lc, s_rc);

    // Pass 2: dense gather-write, split by source
    dim3 grid(NS / (256 * 4), BB, 2);
    dense_direct<<<grid, 256, 0, stream>>>(l_feat, r_feat, w_l, w_r,
                                           out_lidar, out_radar, out_cat);
    dense_cen<<<grid, 256, 0, stream>>>(lc_feat, rc_feat, w_lc, w_rc, out_cat);
}